// Round 8
// baseline (125.615 us; speedup 1.0000x reference)
//
#include <hip/hip_runtime.h>

#define TS 64
#define NB 256
#define DI 32
#define NH 10
#define IND 42

typedef float f32x2 __attribute__((ext_vector_type(2)));

// ---- packed-f32 VOP3P helpers (CDNA2+). op_sel[i]: which half of src i
// feeds the LO op; op_sel_hi[i]: which half feeds the HI op. neg_lo/neg_hi
// negate that source in the lo/hi op. All derived+checked vs scalar R18.
#define PKOP2(name, instr, mods) \
__device__ __forceinline__ f32x2 name(f32x2 a, f32x2 b){ \
  f32x2 d; asm(instr " %0, %1, %2 " mods : "=v"(d) : "v"(a), "v"(b)); return d; }
#define PKOP3(name, mods) \
__device__ __forceinline__ f32x2 name(f32x2 a, f32x2 b, f32x2 c){ \
  f32x2 d; asm("v_pk_fma_f32 %0, %1, %2, %3 " mods : "=v"(d) : "v"(a), "v"(b), "v"(c)); return d; }

PKOP2(pk_mul,       "v_pk_mul_f32", "op_sel:[0,0] op_sel_hi:[1,1]")                 // {a.l*b.l, a.h*b.h}
PKOP2(pk_mul_s0hi,  "v_pk_mul_f32", "op_sel:[1,0] op_sel_hi:[1,1]")                 // {a.h*b.l, a.h*b.h}
PKOP2(pk_mul_s0lo,  "v_pk_mul_f32", "op_sel:[0,0] op_sel_hi:[0,1]")                 // {a.l*b.l, a.l*b.h}
PKOP2(pk_mul_s1lo,  "v_pk_mul_f32", "op_sel:[0,0] op_sel_hi:[1,0]")                 // {a.l*b.l, a.h*b.l}
PKOP2(pk_addsub_ll, "v_pk_add_f32", "op_sel:[0,0] op_sel_hi:[0,0] neg_hi:[0,1]")    // {a.l+b.l, a.l-b.l}
PKOP2(pk_addsub_lh, "v_pk_add_f32", "op_sel:[0,1] op_sel_hi:[0,1] neg_hi:[0,1]")    // {a.l+b.h, a.l-b.h}
PKOP3(pk_fma_s1lo,  "op_sel:[0,0,0] op_sel_hi:[1,0,1]")                // {a.l*b.l+c.l, a.h*b.l+c.h}
PKOP3(pk_fma_s1hi,  "op_sel:[0,1,0] op_sel_hi:[1,1,1]")                // {a.l*b.h+c.l, a.h*b.h+c.h}
PKOP3(pk_fma_s1swap,"op_sel:[0,1,0] op_sel_hi:[1,0,1]")                // {a.l*b.h+c.l, a.h*b.l+c.h}
PKOP3(pk_fma_am,    "op_sel:[1,1,0] op_sel_hi:[1,0,1] neg_lo:[1,0,0]") // {-a.h*b.h+c.l, a.h*b.l+c.h}
PKOP3(pk_fma_s0lo,  "op_sel:[0,0,0] op_sel_hi:[0,1,1]")                // {a.l*b.l+c.l, a.l*b.h+c.h}
PKOP3(pk_fma_s0hi,  "op_sel:[1,0,0] op_sel_hi:[1,1,1]")                // {a.h*b.l+c.l, a.h*b.h+c.h}

// DPP quad_perm xor-exchange: 0xB1 = xor1, 0x4E = xor2 (VALU pipe)
template<int CTRL>
__device__ __forceinline__ float dppx(float v){
  return __int_as_float(__builtin_amdgcn_update_dpp(
      0, __float_as_int(v), CTRL, 0xF, 0xF, true));
}
__device__ __forceinline__ float rl(float v, int lane){
  return __int_as_float(__builtin_amdgcn_readlane(__float_as_int(v), lane));
}
__device__ __forceinline__ void pin(float& x){ asm volatile("" : "+v"(x)); }
__device__ __forceinline__ void pinv(f32x2& x){ asm volatile("" : "+v"(x)); }

__device__ __forceinline__ float tanhr(float x){ float e = __expf(2.f*x); return 1.f - 2.f/(e + 1.f); }

// combined U = RY(t3)*RX(t2)*RZ(t1) -> 8 floats (row0 r/i pairs, row1 r/i pairs)
__device__ __forceinline__ void mkU(float t1, float t2, float t3, float* dst){
  float c1 = __cosf(0.5f*t1), s1 = __sinf(0.5f*t1);
  float c2 = __cosf(0.5f*t2), s2 = __sinf(0.5f*t2);
  float c3 = __cosf(0.5f*t3), s3 = __sinf(0.5f*t3);
  float A00r =  c2*c1, A00i = -c2*s1;
  float A01r =  s2*s1, A01i = -s2*c1;
  float A10r = -s2*s1, A10i = -s2*c1;
  float A11r =  c2*c1, A11i =  c2*s1;
  dst[0] = c3*A00r - s3*A10r; dst[1] = c3*A00i - s3*A10i;
  dst[2] = c3*A01r - s3*A11r; dst[3] = c3*A01i - s3*A11i;
  dst[4] = s3*A00r + c3*A10r; dst[5] = s3*A00i + c3*A10i;
  dst[6] = s3*A01r + c3*A11r; dst[7] = s3*A01i + c3*A11i;
}

__device__ __forceinline__ float3 qf(float q00, float q11, float q01){
  return make_float3(0.5f*(q00+q11), 0.5f*(q00-q11), 0.5f*q01);
}

// One block per batch element. Wave g (0..3) = circuit g.
// R19: packed-f32 chain. R18 model: step ~= 1000cyc issue + 1000cyc stall.
// v_pk_{add,mul,fma}_f32 with op_sel/neg maps the (Q,S,A,Bn) chain onto
// pairs P1={Q,S}, P2={A,Bn}: wire body 19 scalar -> 9 pk ops (products
// arranged to round bit-identically to R18). v-broadcast moved from 40
// readlanes/step to a wave-private LDS bounce (same-wave lgkmcnt, no
// barrier) delivering {n0,n1},{e1r,e1i} pre-packed for the pk chain.
__global__ __launch_bounds__(256) __attribute__((amdgpu_waves_per_eu(1, 1)))
void qlstm_kernel(const float* __restrict__ xin,
                  const float* __restrict__ qp,
                  const float* __restrict__ Wf, const float* __restrict__ bfp,
                  const float* __restrict__ Wi, const float* __restrict__ bip,
                  const float* __restrict__ Wg, const float* __restrict__ bgp,
                  const float* __restrict__ Wo, const float* __restrict__ bop,
                  float* __restrict__ out)
{
  __shared__ float lx[TS][DI + 1];                // staged x, +1 pad
  __shared__ float lwx[4][TS][NH];                // precomputed W.x + bias
  __shared__ __align__(16) float lBw[4][NH][4];   // B_w = U2^dag Z U2
  __shared__ __align__(16) float lq[2][NH][4];    // [buf][h][gate] -> b128 read
  __shared__ __align__(8)  f32x2 lvN[4][NH];      // per-step {n0,n1} per wire
  __shared__ __align__(8)  f32x2 lvE[4][NH];      // per-step {e1r,e1i} per wire

  const int tid  = threadIdx.x;
  const int b    = blockIdx.x;
  const int g    = tid >> 6;
  const int lane = tid & 63;
  const int hq   = lane >> 2;        // mask index (valid < 10)
  const int sg   = lane & 3;         // 0:sigma0 1:H1 2:H2 3:sigma3
  const int hrow = (lane < NH) ? lane : 0;

  const float* Wsel = (g==0) ? Wf : (g==1) ? Wi : (g==2) ? Wg : Wo;
  const float* bsel = (g==0) ? bfp : (g==1) ? bip : (g==2) ? bgp : bop;

  // ---- stage x coalesced ----
  for (int i = tid; i < TS*DI; i += 256) {
    int tt = i >> 5, d = i & 31;
    lx[tt][d] = xin[(size_t)tt*(NB*DI) + b*DI + d];
  }
  // ---- layer-2 B matrices ----
  if (lane < NH) {
    float u[8];
    mkU(qp[30 + lane*3 + 0], qp[30 + lane*3 + 1], qp[30 + lane*3 + 2], u);
    float B00 = u[0]*u[0]+u[1]*u[1] - (u[4]*u[4]+u[5]*u[5]);
    float B11 = u[2]*u[2]+u[3]*u[3] - (u[6]*u[6]+u[7]*u[7]);
    float B01r= u[0]*u[2]+u[1]*u[3] - (u[4]*u[6]+u[5]*u[7]);
    float B01i= u[1]*u[2]-u[0]*u[3] - (u[5]*u[6]-u[4]*u[7]);
    *reinterpret_cast<float4*>(&lBw[g][lane][0]) = make_float4(B00,B11,B01r,B01i);
  }
  __syncthreads();

  // ---- precompute W.x + bias for all t (lane == t), wave-private lwx[g] ----
  {
    float acc[NH];
    #pragma unroll
    for (int h = 0; h < NH; h++) acc[h] = bsel[h];
    #pragma unroll
    for (int k = 0; k < DI; k++) {
      float xk = lx[lane][k];
      #pragma unroll
      for (int h = 0; h < NH; h++) acc[h] = fmaf(Wsel[h*IND + k], xk, acc[h]);
    }
    #pragma unroll
    for (int h = 0; h < NH; h++) lwx[g][lane][h] = acc[h];
  }

  // ---- register-resident recurrent weights + conv-data quadratic forms ----
  float wh[NH];
  #pragma unroll
  for (int j = 0; j < NH; j++) wh[j] = Wsel[hrow*IND + DI + j];

  float3 Qn0, Qn1, Qer, Qei;
  {
    float U1[8];
    mkU(qp[hrow*3+0], qp[hrow*3+1], qp[hrow*3+2], U1);
    float r00r=U1[0], r00i=U1[1], r01r=U1[2], r01i=U1[3];
    float r10r=U1[4], r10i=U1[5], r11r=U1[6], r11i=U1[7];
    float P0r,P0i,P1r,P1i, R0r,R0i,R1r,R1i;
    if (lane == 0) {
      P0r=r00r; P0i=r00i; P1r=r01r; P1i=r01i;
      R0r=r10r; R0i=r10i; R1r=r11r; R1i=r11i;
    } else {
      P0r=0.5f*(r00r+r10r); P0i=0.5f*(r00i+r10i);
      P1r=0.5f*(r01r+r11r); P1i=0.5f*(r01i+r11i);
      R0r=0.5f*(r00r-r10r); R0i=0.5f*(r00i-r10i);
      R1r=0.5f*(r01r-r11r); R1i=0.5f*(r01i-r11i);
    }
    Qn0 = qf(P0r*P0r+P0i*P0i, P1r*P1r+P1i*P1i, 2.f*(P0r*P1r+P0i*P1i));
    Qn1 = qf(R0r*R0r+R0i*R0i, R1r*R1r+R1i*R1i, 2.f*(R0r*R1r+R0i*R1i));
    Qer = qf(R0r*P0r+R0i*P0i, R1r*P1r+R1i*P1i,
             (R0r*P1r+R0i*P1i) + (R1r*P0r+R1i*P0i));
    Qei = qf(R0i*P0r-R0r*P0i, R1i*P1r-R1r*P1i,
             (R0i*P1r-R0r*P1i) + (R1i*P0r-R1r*P0i));
  }
  // pairs for the packed qeval: value = alpha + beta*C + gamma*S
  f32x2 QnA, QnB, QnG, QeA, QeB, QeG;
  QnA.x=Qn0.x; QnA.y=Qn1.x;  QnB.x=Qn0.y; QnB.y=Qn1.y;  QnG.x=Qn0.z; QnG.y=Qn1.z;
  QeA.x=Qer.x; QeA.y=Qei.x;  QeB.x=Qer.y; QeB.y=Qei.y;  QeG.x=Qer.z; QeG.y=Qei.z;

  // ---- per-lane chain init constants; pick scale folded in via linearity ----
  float4 b0 = *reinterpret_cast<const float4*>(&lBw[g][0][0]);
  if (hq == 0) b0 = make_float4(1.f, 1.f, 0.f, 0.f);   // E0 mask excludes wire 0
  float k0, k3, ka, kb;
  if      (sg == 0) { k0 = b0.x;  k3 = b0.y;  ka = b0.z; kb = -b0.w; }
  else if (sg == 1) { k0 = b0.z;  k3 = b0.z;  ka = 0.5f*(b0.x + b0.y); kb = 0.f; }
  else if (sg == 2) { k0 = -b0.w; k3 = b0.w;  ka = 0.f;  kb = 0.5f*(b0.y - b0.x); }
  else              { k0 = b0.y;  k3 = b0.x;  ka = b0.z; kb = b0.w; }
  {
    const float gsc = (sg == 0 || sg == 3) ? 0.5f : 1.0f;
    k0 *= gsc; k3 *= gsc; ka *= gsc; kb *= gsc;
  }
  const float ka2 = ka + ka, kb2 = kb + kb;
  f32x2 KA, KB, KC, KD;
  KA.x = k0;   KA.y = k0;
  KB.x = k3;   KB.y = -k3;
  KC.x = ka2;  KC.y = -ka2;
  KD.x = -kb2; KD.y = -kb2;

  // ---- per-wire packed constants ----
  // K1={Cp,Cm} K2={2Cm,2Cp} K3={Cr2,Ci2} K4={-Ci4,Cr4}; masked: {2,0},{0,4},0,0
  f32x2 K1[9], K2[9], K3[9], K4[9];
  #pragma unroll
  for (int w = 1; w <= 9; w++) {
    float4 bb = *reinterpret_cast<const float4*>(&lBw[g][w][0]);
    bool inM = (hq == 0) || (w <= hq);        // M_0={1..9}, M_h={0..h}
    float Cp = inM ? (bb.x + bb.y) : 2.f;
    float Cm = inM ? (bb.x - bb.y) : 0.f;
    float Cr2 = inM ? (bb.z + bb.z) : 0.f;
    float Ci2 = inM ? (bb.w + bb.w) : 0.f;
    K1[w-1].x = Cp;        K1[w-1].y = Cm;
    K2[w-1].x = Cm + Cm;   K2[w-1].y = Cp + Cp;
    K3[w-1].x = Cr2;       K3[w-1].y = Ci2;
    K4[w-1].x = -(Ci2+Ci2); K4[w-1].y = Cr2 + Cr2;
  }

  // ---- pin chain constants into VGPRs (free at 1 wave/EU budget) ----
  #pragma unroll
  for (int w = 0; w < 9; w++) { pinv(K1[w]); pinv(K2[w]); pinv(K3[w]); pinv(K4[w]); }
  #pragma unroll
  for (int j = 0; j < NH; j++) pin(wh[j]);
  pinv(QnA); pinv(QnB); pinv(QnG); pinv(QeA); pinv(QeB); pinv(QeG);
  pinv(KA); pinv(KB); pinv(KC); pinv(KD);

  // wave-uniform activation constants: g==2 -> tanh(x) = 2*sigm(2x) - 1
  const float se = (g == 2) ? -2.f : -1.f;
  const float sa = (g == 2) ?  2.f :  1.f;
  const float sb = (g == 2) ? -1.f :  0.f;

  float cstate = 0.f, hval = 0.f;
  float wxcur = lwx[g][0][hrow];      // prefetched W.x for t=0

  for (int t = 0; t < TS; t++) {
    const int tb = t & 1;

    // ---- (a) pre-activation: prefetched wx + tree-reduced recurrent dot ----
    float h0 = rl(hval,0), h1 = rl(hval,1), h2 = rl(hval,2), h3 = rl(hval,3), h4 = rl(hval,4);
    float h5 = rl(hval,5), h6 = rl(hval,6), h7 = rl(hval,7), h8 = rl(hval,8), h9 = rl(hval,9);
    float p0 = fmaf(wh[1], h1, wh[0]*h0);
    float p1 = fmaf(wh[3], h3, wh[2]*h2);
    float p2 = fmaf(wh[5], h5, wh[4]*h4);
    float p3 = fmaf(wh[7], h7, wh[6]*h6);
    float p4 = fmaf(wh[9], h9, wh[8]*h8);
    float pre = wxcur + ((p0 + p1) + (p2 + p3) + p4);

    wxcur = lwx[g][(t+1) & (TS-1)][hrow];

    // full-angle sin/cos (|pre| small); packed qeval for {n0,n1},{e1r,e1i}
    float th = pre * 0.15915494309189535f;
    f32x2 CS; CS.x = __builtin_amdgcn_cosf(th); CS.y = __builtin_amdgcn_sinf(th);
    f32x2 NP = pk_fma_s1lo(QnB, CS, pk_fma_s1hi(QnG, CS, QnA));
    f32x2 EP = pk_fma_s1lo(QeB, CS, pk_fma_s1hi(QeG, CS, QeA));
    if (lane < NH) { lvN[g][lane] = NP; lvE[g][lane] = EP; }
    // (same-wave visibility via lgkmcnt; no barrier)

    // ---- (c) packed chain: P1={Q,S}, P2={A,Bn} ----
    f32x2 V1 = lvN[g][0], V2 = lvE[g][0];
    f32x2 P1 = pk_fma_s1hi(KB, V1, pk_mul_s1lo(KA, V1));   // {Q,S}
    f32x2 P2 = pk_fma_s1swap(KD, V2, pk_mul(KC, V2));      // {A,Bn}
    #pragma unroll
    for (int w = 1; w <= 9; w++) {
      f32x2 W1 = lvN[g][w], W2 = lvE[g][w];
      f32x2 U  = pk_addsub_ll(P1, P2);          // {Q+A, Q-A}
      f32x2 M  = pk_mul(U, W1);                 // {m0, m3}
      f32x2 T1 = pk_mul_s0hi(P1, W2);           // {S*vr, S*vi}
      f32x2 AB = pk_fma_am(P2, W2, T1);         // {am, bm}
      f32x2 QS = pk_addsub_lh(M, M);            // {q2, s2}
      f32x2 T2 = pk_mul_s0lo(QS, K1[w-1]);      // {q2*Cp, q2*Cm}
      P1 = pk_fma_s0lo(AB, K2[w-1], T2);        // {Q', S'}
      f32x2 T3 = pk_mul_s0hi(QS, K3[w-1]);      // {s2*Cr2, s2*Ci2}
      P2 = pk_fma_s0hi(AB, K4[w-1], T3);        // {A', Bn'}
    }

    // ---- (d) pick (scales pre-folded) + quad-sum; activation PRE-barrier ----
    float Qv = P1.x, Sv = P1.y, Av = P2.x, Bv = P2.y;
    float QpS = Qv + Sv;
    float QmS = Qv - Sv;
    float t0 = (sg & 1) ? Av  : QpS;
    float t1 = (sg & 1) ? QmS : Bv;
    float Ee = (sg & 2) ? t1 : t0;
    Ee += dppx<0xB1>(Ee);
    Ee += dppx<0x4E>(Ee);
    if ((lane & 3) == 0 && hq < NH) {
      lq[tb][hq][g] = fmaf(sa, 1.f/(1.f + __expf(se*Ee)), sb);
    }
    __syncthreads();   // the one barrier: activated-gate exchange

    // ---- (f) LSTM cell: single b128 broadcast read of (f,i,g,o) ----
    float4 gates = *reinterpret_cast<const float4*>(&lq[tb][hrow][0]);
    cstate = gates.x*cstate + gates.y*gates.z;
    hval = gates.w*tanhr(cstate);
    if (g == 0 && lane < NH) out[(size_t)t*(NB*NH) + b*NH + lane] = hval;
  }

  if (g == 0 && lane < NH) {
    out[(size_t)TS*NB*NH + b*NH + lane]          = hval;
    out[(size_t)TS*NB*NH + NB*NH + b*NH + lane]  = cstate;
  }
}

extern "C" void kernel_launch(void* const* d_in, const int* in_sizes, int n_in,
                              void* d_out, int out_size, void* d_ws, size_t ws_size,
                              hipStream_t stream) {
  (void)in_sizes; (void)n_in; (void)d_ws; (void)ws_size; (void)out_size;
  qlstm_kernel<<<dim3(NB), dim3(256), 0, stream>>>(
      (const float*)d_in[0], (const float*)d_in[1],
      (const float*)d_in[2], (const float*)d_in[3],
      (const float*)d_in[4], (const float*)d_in[5],
      (const float*)d_in[6], (const float*)d_in[7],
      (const float*)d_in[8], (const float*)d_in[9],
      (float*)d_out);
}

// Round 9
// 117.302 us; speedup vs baseline: 1.0709x; 1.0709x over previous
//
#include <hip/hip_runtime.h>

#define TS 64
#define NB 256
#define DI 32
#define NH 10
#define IND 42

typedef float f32x2 __attribute__((ext_vector_type(2)));

// ---- packed-f32 VOP3P helpers (CDNA2+). op_sel[i]: which half of src i
// feeds the LO op; op_sel_hi[i]: which half feeds the HI op. neg_lo/neg_hi
// negate that source in the lo/hi op. All derived+checked vs scalar R18.
#define PKOP2(name, instr, mods) \
__device__ __forceinline__ f32x2 name(f32x2 a, f32x2 b){ \
  f32x2 d; asm(instr " %0, %1, %2 " mods : "=v"(d) : "v"(a), "v"(b)); return d; }
#define PKOP3(name, mods) \
__device__ __forceinline__ f32x2 name(f32x2 a, f32x2 b, f32x2 c){ \
  f32x2 d; asm("v_pk_fma_f32 %0, %1, %2, %3 " mods : "=v"(d) : "v"(a), "v"(b), "v"(c)); return d; }

PKOP2(pk_mul,       "v_pk_mul_f32", "op_sel:[0,0] op_sel_hi:[1,1]")                 // {a.l*b.l, a.h*b.h}
PKOP2(pk_mul_s0hi,  "v_pk_mul_f32", "op_sel:[1,0] op_sel_hi:[1,1]")                 // {a.h*b.l, a.h*b.h}
PKOP2(pk_mul_s0lo,  "v_pk_mul_f32", "op_sel:[0,0] op_sel_hi:[0,1]")                 // {a.l*b.l, a.l*b.h}
PKOP2(pk_mul_s1lo,  "v_pk_mul_f32", "op_sel:[0,0] op_sel_hi:[1,0]")                 // {a.l*b.l, a.h*b.l}
PKOP2(pk_addsub_ll, "v_pk_add_f32", "op_sel:[0,0] op_sel_hi:[0,0] neg_hi:[0,1]")    // {a.l+b.l, a.l-b.l}
PKOP2(pk_addsub_lh, "v_pk_add_f32", "op_sel:[0,1] op_sel_hi:[0,1] neg_hi:[0,1]")    // {a.l+b.h, a.l-b.h}
PKOP3(pk_fma_s1lo,  "op_sel:[0,0,0] op_sel_hi:[1,0,1]")                // {a.l*b.l+c.l, a.h*b.l+c.h}
PKOP3(pk_fma_s1hi,  "op_sel:[0,1,0] op_sel_hi:[1,1,1]")                // {a.l*b.h+c.l, a.h*b.h+c.h}
PKOP3(pk_fma_s1swap,"op_sel:[0,1,0] op_sel_hi:[1,0,1]")                // {a.l*b.h+c.l, a.h*b.l+c.h}
PKOP3(pk_fma_am,    "op_sel:[1,1,0] op_sel_hi:[1,0,1] neg_lo:[1,0,0]") // {-a.h*b.h+c.l, a.h*b.l+c.h}
PKOP3(pk_fma_s0lo,  "op_sel:[0,0,0] op_sel_hi:[0,1,1]")                // {a.l*b.l+c.l, a.l*b.h+c.h}
PKOP3(pk_fma_s0hi,  "op_sel:[1,0,0] op_sel_hi:[1,1,1]")                // {a.h*b.l+c.l, a.h*b.h+c.h}

// DPP quad_perm xor-exchange: 0xB1 = xor1, 0x4E = xor2 (VALU pipe)
template<int CTRL>
__device__ __forceinline__ float dppx(float v){
  return __int_as_float(__builtin_amdgcn_update_dpp(
      0, __float_as_int(v), CTRL, 0xF, 0xF, true));
}
__device__ __forceinline__ float rl(float v, int lane){
  return __int_as_float(__builtin_amdgcn_readlane(__float_as_int(v), lane));
}
// broadcast both halves of a pair from a fixed lane
__device__ __forceinline__ f32x2 rl2(f32x2 v, int lane){
  f32x2 r; r.x = rl(v.x, lane); r.y = rl(v.y, lane); return r;
}
__device__ __forceinline__ void pin(float& x){ asm volatile("" : "+v"(x)); }
__device__ __forceinline__ void pinv(f32x2& x){ asm volatile("" : "+v"(x)); }

__device__ __forceinline__ float tanhr(float x){ float e = __expf(2.f*x); return 1.f - 2.f/(e + 1.f); }

// combined U = RY(t3)*RX(t2)*RZ(t1) -> 8 floats (row0 r/i pairs, row1 r/i pairs)
__device__ __forceinline__ void mkU(float t1, float t2, float t3, float* dst){
  float c1 = __cosf(0.5f*t1), s1 = __sinf(0.5f*t1);
  float c2 = __cosf(0.5f*t2), s2 = __sinf(0.5f*t2);
  float c3 = __cosf(0.5f*t3), s3 = __sinf(0.5f*t3);
  float A00r =  c2*c1, A00i = -c2*s1;
  float A01r =  s2*s1, A01i = -s2*c1;
  float A10r = -s2*s1, A10i = -s2*c1;
  float A11r =  c2*c1, A11i =  c2*s1;
  dst[0] = c3*A00r - s3*A10r; dst[1] = c3*A00i - s3*A10i;
  dst[2] = c3*A01r - s3*A11r; dst[3] = c3*A01i - s3*A11i;
  dst[4] = s3*A00r + c3*A10r; dst[5] = s3*A00i + c3*A10i;
  dst[6] = s3*A01r + c3*A11r; dst[7] = s3*A01i + c3*A11i;
}

__device__ __forceinline__ float3 qf(float q00, float q11, float q01){
  return make_float3(0.5f*(q00+q11), 0.5f*(q00-q11), 0.5f*q01);
}

// One block per batch element. Wave g (0..3) = circuit g.
// R20: kill the serial-path stalls the issue-shrink rounds exposed.
// R16/R18/R19 all land at ~57us despite 600/540/350 VALU-instr steps ->
// step time is a serial LATENCY path, not issue. Two structural fixes:
// (1) per-step out[] global store removed from the loop: __syncthreads
//     drains vmcnt(0), so every step serialized on an HBM store retire
//     (~300-500cyc). hval rows now buffered in LDS (lgkm only) and written
//     once, coalesced, after the t-loop.
// (2) R19's LDS bounce (ds_write+lgkmcnt+ds_read on the critical chain)
//     reverted to readlane pair-broadcasts: 40 independent readlanes =
//     pure issue, which is in huge surplus (VALUBusy 30%).
// Packed (Q,S)/(A,Bn) chain and all R18/R19 algebra retained.
__global__ __launch_bounds__(256) __attribute__((amdgpu_waves_per_eu(1, 1)))
void qlstm_kernel(const float* __restrict__ xin,
                  const float* __restrict__ qp,
                  const float* __restrict__ Wf, const float* __restrict__ bfp,
                  const float* __restrict__ Wi, const float* __restrict__ bip,
                  const float* __restrict__ Wg, const float* __restrict__ bgp,
                  const float* __restrict__ Wo, const float* __restrict__ bop,
                  float* __restrict__ out)
{
  __shared__ float lx[TS][DI + 1];                // staged x, +1 pad
  __shared__ float lwx[4][TS][NH];                // precomputed W.x + bias
  __shared__ __align__(16) float lBw[4][NH][4];   // B_w = U2^dag Z U2
  __shared__ __align__(16) float lq[2][NH][4];    // [buf][h][gate] -> b128 read
  __shared__ float lhout[TS][NH];                 // buffered h-outputs

  const int tid  = threadIdx.x;
  const int b    = blockIdx.x;
  const int g    = tid >> 6;
  const int lane = tid & 63;
  const int hq   = lane >> 2;        // mask index (valid < 10)
  const int sg   = lane & 3;         // 0:sigma0 1:H1 2:H2 3:sigma3
  const int hrow = (lane < NH) ? lane : 0;

  const float* Wsel = (g==0) ? Wf : (g==1) ? Wi : (g==2) ? Wg : Wo;
  const float* bsel = (g==0) ? bfp : (g==1) ? bip : (g==2) ? bgp : bop;

  // ---- stage x coalesced ----
  for (int i = tid; i < TS*DI; i += 256) {
    int tt = i >> 5, d = i & 31;
    lx[tt][d] = xin[(size_t)tt*(NB*DI) + b*DI + d];
  }
  // ---- layer-2 B matrices ----
  if (lane < NH) {
    float u[8];
    mkU(qp[30 + lane*3 + 0], qp[30 + lane*3 + 1], qp[30 + lane*3 + 2], u);
    float B00 = u[0]*u[0]+u[1]*u[1] - (u[4]*u[4]+u[5]*u[5]);
    float B11 = u[2]*u[2]+u[3]*u[3] - (u[6]*u[6]+u[7]*u[7]);
    float B01r= u[0]*u[2]+u[1]*u[3] - (u[4]*u[6]+u[5]*u[7]);
    float B01i= u[1]*u[2]-u[0]*u[3] - (u[5]*u[6]-u[4]*u[7]);
    *reinterpret_cast<float4*>(&lBw[g][lane][0]) = make_float4(B00,B11,B01r,B01i);
  }
  __syncthreads();

  // ---- precompute W.x + bias for all t (lane == t), wave-private lwx[g] ----
  {
    float acc[NH];
    #pragma unroll
    for (int h = 0; h < NH; h++) acc[h] = bsel[h];
    #pragma unroll
    for (int k = 0; k < DI; k++) {
      float xk = lx[lane][k];
      #pragma unroll
      for (int h = 0; h < NH; h++) acc[h] = fmaf(Wsel[h*IND + k], xk, acc[h]);
    }
    #pragma unroll
    for (int h = 0; h < NH; h++) lwx[g][lane][h] = acc[h];
  }

  // ---- register-resident recurrent weights + conv-data quadratic forms ----
  float wh[NH];
  #pragma unroll
  for (int j = 0; j < NH; j++) wh[j] = Wsel[hrow*IND + DI + j];

  float3 Qn0, Qn1, Qer, Qei;
  {
    float U1[8];
    mkU(qp[hrow*3+0], qp[hrow*3+1], qp[hrow*3+2], U1);
    float r00r=U1[0], r00i=U1[1], r01r=U1[2], r01i=U1[3];
    float r10r=U1[4], r10i=U1[5], r11r=U1[6], r11i=U1[7];
    float P0r,P0i,P1r,P1i, R0r,R0i,R1r,R1i;
    if (lane == 0) {
      P0r=r00r; P0i=r00i; P1r=r01r; P1i=r01i;
      R0r=r10r; R0i=r10i; R1r=r11r; R1i=r11i;
    } else {
      P0r=0.5f*(r00r+r10r); P0i=0.5f*(r00i+r10i);
      P1r=0.5f*(r01r+r11r); P1i=0.5f*(r01i+r11i);
      R0r=0.5f*(r00r-r10r); R0i=0.5f*(r00i-r10i);
      R1r=0.5f*(r01r-r11r); R1i=0.5f*(r01i-r11i);
    }
    Qn0 = qf(P0r*P0r+P0i*P0i, P1r*P1r+P1i*P1i, 2.f*(P0r*P1r+P0i*P1i));
    Qn1 = qf(R0r*R0r+R0i*R0i, R1r*R1r+R1i*R1i, 2.f*(R0r*R1r+R0i*R1i));
    Qer = qf(R0r*P0r+R0i*P0i, R1r*P1r+R1i*P1i,
             (R0r*P1r+R0i*P1i) + (R1r*P0r+R1i*P0i));
    Qei = qf(R0i*P0r-R0r*P0i, R1i*P1r-R1r*P1i,
             (R0i*P1r-R0r*P1i) + (R1i*P0r-R1r*P0i));
  }
  // pairs for the packed qeval: value = alpha + beta*C + gamma*S
  f32x2 QnA, QnB, QnG, QeA, QeB, QeG;
  QnA.x=Qn0.x; QnA.y=Qn1.x;  QnB.x=Qn0.y; QnB.y=Qn1.y;  QnG.x=Qn0.z; QnG.y=Qn1.z;
  QeA.x=Qer.x; QeA.y=Qei.x;  QeB.x=Qer.y; QeB.y=Qei.y;  QeG.x=Qer.z; QeG.y=Qei.z;

  // ---- per-lane chain init constants; pick scale folded in via linearity ----
  float4 b0 = *reinterpret_cast<const float4*>(&lBw[g][0][0]);
  if (hq == 0) b0 = make_float4(1.f, 1.f, 0.f, 0.f);   // E0 mask excludes wire 0
  float k0, k3, ka, kb;
  if      (sg == 0) { k0 = b0.x;  k3 = b0.y;  ka = b0.z; kb = -b0.w; }
  else if (sg == 1) { k0 = b0.z;  k3 = b0.z;  ka = 0.5f*(b0.x + b0.y); kb = 0.f; }
  else if (sg == 2) { k0 = -b0.w; k3 = b0.w;  ka = 0.f;  kb = 0.5f*(b0.y - b0.x); }
  else              { k0 = b0.y;  k3 = b0.x;  ka = b0.z; kb = b0.w; }
  {
    const float gsc = (sg == 0 || sg == 3) ? 0.5f : 1.0f;
    k0 *= gsc; k3 *= gsc; ka *= gsc; kb *= gsc;
  }
  const float ka2 = ka + ka, kb2 = kb + kb;
  f32x2 KA, KB, KC, KD;
  KA.x = k0;   KA.y = k0;
  KB.x = k3;   KB.y = -k3;
  KC.x = ka2;  KC.y = -ka2;
  KD.x = -kb2; KD.y = -kb2;

  // ---- per-wire packed constants ----
  // K1={Cp,Cm} K2={2Cm,2Cp} K3={Cr2,Ci2} K4={-Ci4,Cr4}; masked: {2,0},{0,4},0,0
  f32x2 K1[9], K2[9], K3[9], K4[9];
  #pragma unroll
  for (int w = 1; w <= 9; w++) {
    float4 bb = *reinterpret_cast<const float4*>(&lBw[g][w][0]);
    bool inM = (hq == 0) || (w <= hq);        // M_0={1..9}, M_h={0..h}
    float Cp = inM ? (bb.x + bb.y) : 2.f;
    float Cm = inM ? (bb.x - bb.y) : 0.f;
    float Cr2 = inM ? (bb.z + bb.z) : 0.f;
    float Ci2 = inM ? (bb.w + bb.w) : 0.f;
    K1[w-1].x = Cp;        K1[w-1].y = Cm;
    K2[w-1].x = Cm + Cm;   K2[w-1].y = Cp + Cp;
    K3[w-1].x = Cr2;       K3[w-1].y = Ci2;
    K4[w-1].x = -(Ci2+Ci2); K4[w-1].y = Cr2 + Cr2;
  }

  // ---- pin chain constants into VGPRs (free at 1 wave/EU budget) ----
  #pragma unroll
  for (int w = 0; w < 9; w++) { pinv(K1[w]); pinv(K2[w]); pinv(K3[w]); pinv(K4[w]); }
  #pragma unroll
  for (int j = 0; j < NH; j++) pin(wh[j]);
  pinv(QnA); pinv(QnB); pinv(QnG); pinv(QeA); pinv(QeB); pinv(QeG);
  pinv(KA); pinv(KB); pinv(KC); pinv(KD);

  // wave-uniform activation constants: g==2 -> tanh(x) = 2*sigm(2x) - 1
  const float se = (g == 2) ? -2.f : -1.f;
  const float sa = (g == 2) ?  2.f :  1.f;
  const float sb = (g == 2) ? -1.f :  0.f;

  float cstate = 0.f, hval = 0.f;
  float wxcur = lwx[g][0][hrow];      // prefetched W.x for t=0

  for (int t = 0; t < TS; t++) {
    const int tb = t & 1;

    // ---- (a) pre-activation: prefetched wx + tree-reduced recurrent dot ----
    float h0 = rl(hval,0), h1 = rl(hval,1), h2 = rl(hval,2), h3 = rl(hval,3), h4 = rl(hval,4);
    float h5 = rl(hval,5), h6 = rl(hval,6), h7 = rl(hval,7), h8 = rl(hval,8), h9 = rl(hval,9);
    float p0 = fmaf(wh[1], h1, wh[0]*h0);
    float p1 = fmaf(wh[3], h3, wh[2]*h2);
    float p2 = fmaf(wh[5], h5, wh[4]*h4);
    float p3 = fmaf(wh[7], h7, wh[6]*h6);
    float p4 = fmaf(wh[9], h9, wh[8]*h8);
    float pre = wxcur + ((p0 + p1) + (p2 + p3) + p4);

    wxcur = lwx[g][(t+1) & (TS-1)][hrow];

    // full-angle sin/cos (|pre| small); packed qeval for {n0,n1},{e1r,e1i}
    float th = pre * 0.15915494309189535f;
    f32x2 CS; CS.x = __builtin_amdgcn_cosf(th); CS.y = __builtin_amdgcn_sinf(th);
    f32x2 NP = pk_fma_s1lo(QnB, CS, pk_fma_s1hi(QnG, CS, QnA));
    f32x2 EP = pk_fma_s1lo(QeB, CS, pk_fma_s1hi(QeG, CS, QeA));

    // ---- (c) packed chain: P1={Q,S}, P2={A,Bn}; v's via readlane pairs ----
    f32x2 V1 = rl2(NP, 0), V2 = rl2(EP, 0);
    f32x2 P1 = pk_fma_s1hi(KB, V1, pk_mul_s1lo(KA, V1));   // {Q,S}
    f32x2 P2 = pk_fma_s1swap(KD, V2, pk_mul(KC, V2));      // {A,Bn}
    #pragma unroll
    for (int w = 1; w <= 9; w++) {
      f32x2 W1 = rl2(NP, w), W2 = rl2(EP, w);
      f32x2 U  = pk_addsub_ll(P1, P2);          // {Q+A, Q-A}
      f32x2 M  = pk_mul(U, W1);                 // {m0, m3}
      f32x2 T1 = pk_mul_s0hi(P1, W2);           // {S*vr, S*vi}
      f32x2 AB = pk_fma_am(P2, W2, T1);         // {am, bm}
      f32x2 QS = pk_addsub_lh(M, M);            // {q2, s2}
      f32x2 T2 = pk_mul_s0lo(QS, K1[w-1]);      // {q2*Cp, q2*Cm}
      P1 = pk_fma_s0lo(AB, K2[w-1], T2);        // {Q', S'}
      f32x2 T3 = pk_mul_s0hi(QS, K3[w-1]);      // {s2*Cr2, s2*Ci2}
      P2 = pk_fma_s0hi(AB, K4[w-1], T3);        // {A', Bn'}
    }

    // ---- (d) pick (scales pre-folded) + quad-sum; activation PRE-barrier ----
    float Qv = P1.x, Sv = P1.y, Av = P2.x, Bv = P2.y;
    float QpS = Qv + Sv;
    float QmS = Qv - Sv;
    float t0 = (sg & 1) ? Av  : QpS;
    float t1 = (sg & 1) ? QmS : Bv;
    float Ee = (sg & 2) ? t1 : t0;
    Ee += dppx<0xB1>(Ee);
    Ee += dppx<0x4E>(Ee);
    if ((lane & 3) == 0 && hq < NH) {
      lq[tb][hq][g] = fmaf(sa, 1.f/(1.f + __expf(se*Ee)), sb);
    }
    __syncthreads();   // the one barrier (no vmem in flight: lgkm-only drain)

    // ---- (f) LSTM cell: single b128 broadcast read of (f,i,g,o) ----
    float4 gates = *reinterpret_cast<const float4*>(&lq[tb][hrow][0]);
    cstate = gates.x*cstate + gates.y*gates.z;
    hval = gates.w*tanhr(cstate);
    // buffer h-output in LDS (lgkm only) -- written to HBM after the loop
    if (g == 0 && lane < NH) lhout[t][lane] = hval;
  }

  // ---- bulk coalesced h-output write (off the serial path) ----
  __syncthreads();
  for (int i = tid; i < TS*NH; i += 256) {
    int tt = i / NH, h = i - tt*NH;
    out[(size_t)tt*(NB*NH) + b*NH + h] = lhout[tt][h];
  }
  if (g == 0 && lane < NH) {
    out[(size_t)TS*NB*NH + b*NH + lane]          = hval;
    out[(size_t)TS*NB*NH + NB*NH + b*NH + lane]  = cstate;
  }
}

extern "C" void kernel_launch(void* const* d_in, const int* in_sizes, int n_in,
                              void* d_out, int out_size, void* d_ws, size_t ws_size,
                              hipStream_t stream) {
  (void)in_sizes; (void)n_in; (void)d_ws; (void)ws_size; (void)out_size;
  qlstm_kernel<<<dim3(NB), dim3(256), 0, stream>>>(
      (const float*)d_in[0], (const float*)d_in[1],
      (const float*)d_in[2], (const float*)d_in[3],
      (const float*)d_in[4], (const float*)d_in[5],
      (const float*)d_in[6], (const float*)d_in[7],
      (const float*)d_in[8], (const float*)d_in[9],
      (float*)d_out);
}